// Round 3
// baseline (103.678 us; speedup 1.0000x reference)
//
#include <hip/hip_runtime.h>
#include <hip/hip_bf16.h>

// Problem shape (fixed by setup_inputs): B=2, H=8, T=1024, P=64
#define TDIM 1024
#define PDIM 64
#define BHN  16     // B*H
#define NCH  64     // chunks along T
#define CHS  16     // chunk size (NCH*CHS == TDIM)

typedef __bf16 bf16_t;
typedef bf16_t bf16x8 __attribute__((ext_vector_type(8)));
typedef float  floatx4 __attribute__((ext_vector_type(4)));

__device__ __forceinline__ floatx4 mfma16(bf16x8 a, bf16x8 b, floatx4 c) {
    return __builtin_amdgcn_mfma_f32_16x16x32_bf16(a, b, c, 0, 0, 0);
}

// ---------------------------------------------------------------------------
// A1: per-(bh, chunk) stats: chunk max of K and chunk sum of exp(2K), per p.
// grid = BHN*NCH = 1024 blocks of 64 threads (lane = p) -> 4 waves/CU.
// ---------------------------------------------------------------------------
__global__ __launch_bounds__(64) void stats_kernel(
        const float* __restrict__ K,
        float* __restrict__ cmax, float* __restrict__ csum) {
    int bh = blockIdx.x >> 6;
    int c  = blockIdx.x & 63;
    int p  = threadIdx.x;
    const float* Kb = K + (size_t)bh * TDIM * PDIM + (size_t)c * CHS * PDIM + p;
    float k[CHS];
#pragma unroll
    for (int i = 0; i < CHS; ++i) k[i] = Kb[i * PDIM];
    float m = -INFINITY, s = 0.f;
#pragma unroll
    for (int i = 0; i < CHS; ++i) {
        m = fmaxf(m, k[i]);
        float e = __expf(k[i]);
        s += e * e;
    }
    cmax[(bh * NCH + c) * PDIM + p] = m;
    csum[(bh * NCH + c) * PDIM + p] = s;
}

// ---------------------------------------------------------------------------
// A2: seeded within-chunk sequential scan (CHS=16 steps). Emits:
//   W[bh][t][p]  = bf16( exp(Q - m_cum) )        (natural layout)
//   U[bh][t][p]  = bf16( V * exp(K) )            (natural layout)
//   Kft[bh][q][t]= bf16( exp(K[t][q]) )          (TRANSPOSED, via LDS tile)
//   den[bh][t]   = fp32 sum_p W*S2cum            (post-loop LDS reduce)
// grid = BHN*NCH = 1024 blocks of 64 threads (lane = p).
// ---------------------------------------------------------------------------
__global__ __launch_bounds__(64) void feat_kernel(
        const float* __restrict__ Q, const float* __restrict__ K,
        const float* __restrict__ V,
        const float* __restrict__ cmax, const float* __restrict__ csum,
        bf16_t* __restrict__ W, bf16_t* __restrict__ U,
        bf16_t* __restrict__ Kft, float* __restrict__ den) {
    int bh = blockIdx.x >> 6;
    int c  = blockIdx.x & 63;
    int p  = threadIdx.x;
    size_t base = (size_t)bh * TDIM * PDIM;
    int t0 = c * CHS;

    float m = -INFINITY, s = 0.f;
#pragma unroll 8
    for (int cc = 0; cc < c; ++cc) {
        m = fmaxf(m, cmax[(bh * NCH + cc) * PDIM + p]);
        s += csum[(bh * NCH + cc) * PDIM + p];
    }

    float kq[CHS], qq_[CHS], vv[CHS];
#pragma unroll
    for (int i = 0; i < CHS; ++i) {
        kq[i]  = K[base + (size_t)(t0 + i) * PDIM + p];
        qq_[i] = Q[base + (size_t)(t0 + i) * PDIM + p];
        vv[i]  = V[base + (size_t)(t0 + i) * PDIM + p];
    }

    __shared__ bf16_t ek_t[CHS][PDIM + 4];   // [t_local][p]
    __shared__ float  dt[CHS][PDIM + 1];     // per-(t,p) den contribution

#pragma unroll
    for (int i = 0; i < CHS; ++i) {
        int t = t0 + i;
        m = fmaxf(m, kq[i]);
        float ek = __expf(kq[i]);
        s += ek * ek;                         // inclusive running sum of exp(2K)
        float w = __expf(qq_[i] - m);         // inclusive running max
        W[base + (size_t)t * PDIM + p] = (bf16_t)w;
        U[base + (size_t)t * PDIM + p] = (bf16_t)(vv[i] * ek);
        ek_t[i][p] = (bf16_t)ek;
        dt[i][p] = w * s;
    }
    __syncthreads();

    // den reduce: lane l -> t = l>>2, g = l&3; partial over p = 4*i+g
    {
        int tl = p >> 2, g = p & 3;
        float d = 0.f;
#pragma unroll
        for (int i = 0; i < 16; ++i) d += dt[tl][i * 4 + g];
        d += __shfl_xor(d, 1);
        d += __shfl_xor(d, 2);
        if (g == 0) den[bh * TDIM + t0 + tl] = d;
    }

    // transposed Kft write
    {
        int hi = p >> 4, tl = p & 15;
#pragma unroll
        for (int it = 0; it < 16; ++it) {
            int q = it * 4 + hi;
            Kft[((size_t)bh * PDIM + q) * TDIM + t0 + tl] = ek_t[tl][q];
        }
    }
}

// ---------------------------------------------------------------------------
// B: per-(bh, 64-row tile) causal double matmul — LDS-free operand path.
//   8 waves: wave = par*4 + sub. sub = 16-row substrip, par = kt parity
//   (2-way split-K across waves). All MFMA A/B fragments are 16B-contiguous
//   in W / U / Kft layouts -> direct global int4 loads, NO staging barriers.
//   Per-wave Ct round-trip (C/D layout -> A-operand layout) in private LDS.
//   Two block barriers total: cross-parity fp32 reduce + epilogue.
// grid = i*16 + bh (256 blocks of 512 thr); XCD = blockIdx%8 = bh%8 -> each
// XCD sees only 2 bh (768 KB working set, fits its 4 MB L2).
// ---------------------------------------------------------------------------
__global__ __launch_bounds__(512, 2) void attn_kernel(
        const bf16_t* __restrict__ W, const bf16_t* __restrict__ U,
        const bf16_t* __restrict__ Kft, const float* __restrict__ den,
        float* __restrict__ out) {
    int bh  = blockIdx.x & 15;
    int i   = blockIdx.x >> 4;   // row tile index 0..15
    int tid = threadIdx.x;
    int wave = tid >> 6, lane = tid & 63;
    int lq = lane & 15, qd = lane >> 4;
    int sub = wave & 3;          // substrip: rows [16*sub, 16*sub+16) of tile
    int par = wave >> 2;         // kt parity handled by this wave
    int b = bh >> 3, h = bh & 7;

    __shared__ bf16_t Ct[8][16][72];     // per-wave C round-trip buffer
    __shared__ float  Yred[4][16][68];   // par=1 partial sums (pad 68 vs conflicts)
    __shared__ float  denb[64];

    size_t base = (size_t)bh * TDIM * PDIM;
    int trow0 = i * 64 + sub * 16;       // global t of substrip row 0

    if (tid < 64) denb[tid] = den[bh * TDIM + i * 64 + tid];

    // W A-fragments: A[m=lq][k=qd*8+e], rows are this substrip's 16 t-rows
    const bf16_t* wrow = W + base + (size_t)(trow0 + lq) * PDIM;
    bf16x8 a0 = *(const bf16x8*)(wrow + qd * 8);
    bf16x8 a1 = *(const bf16x8*)(wrow + 32 + qd * 8);

    floatx4 acc[4];
#pragma unroll
    for (int j = 0; j < 4; ++j) acc[j] = (floatx4){0.f, 0.f, 0.f, 0.f};

    for (int kt = par; kt <= i; kt += 2) {
        // ---- operand fragments, direct global -> VGPR ----
        bf16x8 ub[8], kb[8];
        const bf16_t* ubase = U + base + (size_t)(kt * 64) * PDIM;
        const bf16_t* kbase = Kft + (size_t)bh * PDIM * TDIM + kt * 64;
#pragma unroll
        for (int j = 0; j < 4; ++j) {   // U first: phase1 waits only on these
            const bf16_t* ur = ubase + (size_t)(j * 16 + lq) * PDIM;
            ub[2 * j]     = *(const bf16x8*)(ur + qd * 8);
            ub[2 * j + 1] = *(const bf16x8*)(ur + 32 + qd * 8);
        }
#pragma unroll
        for (int j = 0; j < 4; ++j) {   // Kft stays in flight under phase1
            const bf16_t* kr = kbase + (size_t)(j * 16 + lq) * TDIM;
            kb[2 * j]     = *(const bf16x8*)(kr + qd * 8);
            kb[2 * j + 1] = *(const bf16x8*)(kr + 32 + qd * 8);
        }

        // ---- phase 1: C[16 x 64] = W_sub . U_tile^T ----
        floatx4 cc[4];
#pragma unroll
        for (int j = 0; j < 4; ++j) {
            floatx4 t = (floatx4){0.f, 0.f, 0.f, 0.f};
            t = mfma16(a0, ub[2 * j], t);
            t = mfma16(a1, ub[2 * j + 1], t);
            cc[j] = t;
        }

        // ---- causal mask + C -> per-wave LDS (C/D: row=qd*4+r, col=lq) ----
#pragma unroll
        for (int j = 0; j < 4; ++j) {
#pragma unroll
            for (int r = 0; r < 4; ++r) {
                float v = cc[j][r];
                if (kt == i && (kt * 64 + j * 16 + lq) > (trow0 + qd * 4 + r))
                    v = 0.f;             // strictly-future masked
                Ct[wave][qd * 4 + r][j * 16 + lq] = (bf16_t)v;
            }
        }
        // same-wave write->read: compiler-inserted lgkmcnt, no barrier

        // ---- phase 2: Y_sub += C . Kf_tile ----
        bf16x8 ca0 = *(const bf16x8*)&Ct[wave][lq][qd * 8];
        bf16x8 ca1 = *(const bf16x8*)&Ct[wave][lq][32 + qd * 8];
#pragma unroll
        for (int j = 0; j < 4; ++j) {
            acc[j] = mfma16(ca0, kb[2 * j], acc[j]);
            acc[j] = mfma16(ca1, kb[2 * j + 1], acc[j]);
        }
    }

    // ---- cross-parity reduce + epilogue ----
    if (par == 1) {
#pragma unroll
        for (int j = 0; j < 4; ++j)
#pragma unroll
            for (int r = 0; r < 4; ++r)
                Yred[sub][qd * 4 + r][j * 16 + lq] = acc[j][r];
    }
    __syncthreads();
    if (par == 0) {
#pragma unroll
        for (int j = 0; j < 4; ++j) {
#pragma unroll
            for (int r = 0; r < 4; ++r) {
                int trow_l = sub * 16 + qd * 4 + r;
                int tg = i * 64 + trow_l;
                float y = acc[j][r] + Yred[sub][qd * 4 + r][j * 16 + lq];
                y = y / (denb[trow_l] + 1e-6f);
                out[((size_t)b * TDIM + tg) * (8 * PDIM) + h * PDIM + j * 16 + lq] = y;
            }
        }
    }
}

// ---------------------------------------------------------------------------
extern "C" void kernel_launch(void* const* d_in, const int* in_sizes, int n_in,
                              void* d_out, int out_size, void* d_ws, size_t ws_size,
                              hipStream_t stream) {
    const float* Q = (const float*)d_in[0];
    const float* K = (const float*)d_in[1];
    const float* V = (const float*)d_in[2];
    float* out = (float*)d_out;

    bf16_t* Wf   = (bf16_t*)d_ws;                       // 2 MB
    bf16_t* Uf   = Wf + (size_t)BHN * TDIM * PDIM;      // 2 MB
    bf16_t* Kft  = Uf + (size_t)BHN * TDIM * PDIM;      // 2 MB
    float*  den  = (float*)(Kft + (size_t)BHN * TDIM * PDIM);  // 64 KB
    float*  cmax = den + (size_t)BHN * TDIM;            // 256 KB
    float*  csum = cmax + (size_t)BHN * NCH * PDIM;     // 256 KB

    stats_kernel<<<BHN * NCH, 64, 0, stream>>>(K, cmax, csum);
    feat_kernel<<<BHN * NCH, 64, 0, stream>>>(Q, K, V, cmax, csum, Wf, Uf, Kft, den);
    attn_kernel<<<256, 512, 0, stream>>>(Wf, Uf, Kft, den, out);
}

// Round 4
// 103.062 us; speedup vs baseline: 1.0060x; 1.0060x over previous
//
#include <hip/hip_runtime.h>
#include <hip/hip_bf16.h>

// Problem shape (fixed by setup_inputs): B=2, H=8, T=1024, P=64
#define TDIM 1024
#define PDIM 64
#define BHN  16     // B*H
#define NCH  64     // chunks along T
#define CHS  16     // chunk size (NCH*CHS == TDIM)

typedef __bf16 bf16_t;
typedef bf16_t bf16x8 __attribute__((ext_vector_type(8)));
typedef float  floatx4 __attribute__((ext_vector_type(4)));

__device__ __forceinline__ floatx4 mfma16(bf16x8 a, bf16x8 b, floatx4 c) {
    return __builtin_amdgcn_mfma_f32_16x16x32_bf16(a, b, c, 0, 0, 0);
}

// ---------------------------------------------------------------------------
// A1: per-(bh, chunk) stats: chunk max of K and chunk sum of exp(2K), per p.
// grid = BHN*NCH = 1024 blocks of 64 threads (lane = p) -> 4 waves/CU.
// ---------------------------------------------------------------------------
__global__ __launch_bounds__(64) void stats_kernel(
        const float* __restrict__ K,
        float* __restrict__ cmax, float* __restrict__ csum) {
    int bh = blockIdx.x >> 6;
    int c  = blockIdx.x & 63;
    int p  = threadIdx.x;
    const float* Kb = K + (size_t)bh * TDIM * PDIM + (size_t)c * CHS * PDIM + p;
    float k[CHS];
#pragma unroll
    for (int i = 0; i < CHS; ++i) k[i] = Kb[i * PDIM];
    float m = -INFINITY, s = 0.f;
#pragma unroll
    for (int i = 0; i < CHS; ++i) {
        m = fmaxf(m, k[i]);
        float e = __expf(k[i]);
        s += e * e;
    }
    cmax[(bh * NCH + c) * PDIM + p] = m;
    csum[(bh * NCH + c) * PDIM + p] = s;
}

// ---------------------------------------------------------------------------
// A2: seeded within-chunk sequential scan (CHS=16 steps). Emits:
//   W[bh][t][p]  = bf16( exp(Q - m_cum) )        (natural layout)
//   U[bh][t][p]  = bf16( V * exp(K) )            (natural layout)
//   Kft[bh][q][t]= bf16( exp(K[t][q]) )          (TRANSPOSED, via LDS tile)
//   den[bh][t]   = fp32 sum_p W*S2cum            (post-loop LDS reduce)
// grid = BHN*NCH = 1024 blocks of 64 threads (lane = p).
// ---------------------------------------------------------------------------
__global__ __launch_bounds__(64) void feat_kernel(
        const float* __restrict__ Q, const float* __restrict__ K,
        const float* __restrict__ V,
        const float* __restrict__ cmax, const float* __restrict__ csum,
        bf16_t* __restrict__ W, bf16_t* __restrict__ U,
        bf16_t* __restrict__ Kft, float* __restrict__ den) {
    int bh = blockIdx.x >> 6;
    int c  = blockIdx.x & 63;
    int p  = threadIdx.x;
    size_t base = (size_t)bh * TDIM * PDIM;
    int t0 = c * CHS;

    float m = -INFINITY, s = 0.f;
#pragma unroll 8
    for (int cc = 0; cc < c; ++cc) {
        m = fmaxf(m, cmax[(bh * NCH + cc) * PDIM + p]);
        s += csum[(bh * NCH + cc) * PDIM + p];
    }

    float kq[CHS], qq_[CHS], vv[CHS];
#pragma unroll
    for (int i = 0; i < CHS; ++i) {
        kq[i]  = K[base + (size_t)(t0 + i) * PDIM + p];
        qq_[i] = Q[base + (size_t)(t0 + i) * PDIM + p];
        vv[i]  = V[base + (size_t)(t0 + i) * PDIM + p];
    }

    __shared__ bf16_t ek_t[CHS][PDIM + 4];   // [t_local][p]
    __shared__ float  dt[CHS][PDIM + 1];     // per-(t,p) den contribution

#pragma unroll
    for (int i = 0; i < CHS; ++i) {
        int t = t0 + i;
        m = fmaxf(m, kq[i]);
        float ek = __expf(kq[i]);
        s += ek * ek;                         // inclusive running sum of exp(2K)
        float w = __expf(qq_[i] - m);         // inclusive running max
        W[base + (size_t)t * PDIM + p] = (bf16_t)w;
        U[base + (size_t)t * PDIM + p] = (bf16_t)(vv[i] * ek);
        ek_t[i][p] = (bf16_t)ek;
        dt[i][p] = w * s;
    }
    __syncthreads();

    // den reduce: lane l -> t = l>>2, g = l&3; partial over p = 4*i+g
    {
        int tl = p >> 2, g = p & 3;
        float d = 0.f;
#pragma unroll
        for (int i = 0; i < 16; ++i) d += dt[tl][i * 4 + g];
        d += __shfl_xor(d, 1);
        d += __shfl_xor(d, 2);
        if (g == 0) den[bh * TDIM + t0 + tl] = d;
    }

    // transposed Kft write
    {
        int hi = p >> 4, tl = p & 15;
#pragma unroll
        for (int it = 0; it < 16; ++it) {
            int q = it * 4 + hi;
            Kft[((size_t)bh * PDIM + q) * TDIM + t0 + tl] = ek_t[tl][q];
        }
    }
}

// ---------------------------------------------------------------------------
// B: per-(bh, 64-row tile) causal double matmul — LDS-free operand path.
//   8 waves: wave = par*4 + sub. sub = 16-row substrip, par = kt parity
//   (2-way split-K across waves). All MFMA A/B fragments are 16B-contiguous
//   in W / U / Kft layouts -> direct global int4 loads, NO staging barriers.
//   Per-wave Ct round-trip (C/D layout -> A-operand layout) in private LDS.
//   Two block barriers total: cross-parity fp32 reduce + epilogue.
// NOTE: __launch_bounds__(512) only — NO min-waves arg. R3 used (512,2),
// which demands 4 waves/SIMD co-residency -> 128-VGPR cap -> ~40 VGPRs of
// scratch spills in the hot loop (live set ~170) -> +10 us regression.
// With 512-thread blocks the compiler caps at 256 VGPRs (2 waves/SIMD),
// which holds the live set spill-free.
// grid = i*16 + bh (256 blocks of 512 thr); XCD = blockIdx%8 = bh%8 -> each
// XCD sees only 2 bh (768 KB working set, fits its 4 MB L2).
// ---------------------------------------------------------------------------
__global__ __launch_bounds__(512) void attn_kernel(
        const bf16_t* __restrict__ W, const bf16_t* __restrict__ U,
        const bf16_t* __restrict__ Kft, const float* __restrict__ den,
        float* __restrict__ out) {
    int bh  = blockIdx.x & 15;
    int i   = blockIdx.x >> 4;   // row tile index 0..15
    int tid = threadIdx.x;
    int wave = tid >> 6, lane = tid & 63;
    int lq = lane & 15, qd = lane >> 4;
    int sub = wave & 3;          // substrip: rows [16*sub, 16*sub+16) of tile
    int par = wave >> 2;         // kt parity handled by this wave
    int b = bh >> 3, h = bh & 7;

    __shared__ bf16_t Ct[8][16][72];     // per-wave C round-trip buffer
    __shared__ float  Yred[4][16][68];   // par=1 partial sums (pad 68 vs conflicts)
    __shared__ float  denb[64];

    size_t base = (size_t)bh * TDIM * PDIM;
    int trow0 = i * 64 + sub * 16;       // global t of substrip row 0

    if (tid < 64) denb[tid] = den[bh * TDIM + i * 64 + tid];

    // W A-fragments: A[m=lq][k=qd*8+e], rows are this substrip's 16 t-rows
    const bf16_t* wrow = W + base + (size_t)(trow0 + lq) * PDIM;
    bf16x8 a0 = *(const bf16x8*)(wrow + qd * 8);
    bf16x8 a1 = *(const bf16x8*)(wrow + 32 + qd * 8);

    floatx4 acc[4];
#pragma unroll
    for (int j = 0; j < 4; ++j) acc[j] = (floatx4){0.f, 0.f, 0.f, 0.f};

    for (int kt = par; kt <= i; kt += 2) {
        // ---- operand fragments, direct global -> VGPR ----
        bf16x8 ub[8], kb[8];
        const bf16_t* ubase = U + base + (size_t)(kt * 64) * PDIM;
        const bf16_t* kbase = Kft + (size_t)bh * PDIM * TDIM + kt * 64;
#pragma unroll
        for (int j = 0; j < 4; ++j) {   // U first: phase1 waits only on these
            const bf16_t* ur = ubase + (size_t)(j * 16 + lq) * PDIM;
            ub[2 * j]     = *(const bf16x8*)(ur + qd * 8);
            ub[2 * j + 1] = *(const bf16x8*)(ur + 32 + qd * 8);
        }
#pragma unroll
        for (int j = 0; j < 4; ++j) {   // Kft stays in flight under phase1
            const bf16_t* kr = kbase + (size_t)(j * 16 + lq) * TDIM;
            kb[2 * j]     = *(const bf16x8*)(kr + qd * 8);
            kb[2 * j + 1] = *(const bf16x8*)(kr + 32 + qd * 8);
        }

        // ---- phase 1: C[16 x 64] = W_sub . U_tile^T ----
        floatx4 cc[4];
#pragma unroll
        for (int j = 0; j < 4; ++j) {
            floatx4 t = (floatx4){0.f, 0.f, 0.f, 0.f};
            t = mfma16(a0, ub[2 * j], t);
            t = mfma16(a1, ub[2 * j + 1], t);
            cc[j] = t;
        }

        // ---- causal mask + C -> per-wave LDS (C/D: row=qd*4+r, col=lq) ----
#pragma unroll
        for (int j = 0; j < 4; ++j) {
#pragma unroll
            for (int r = 0; r < 4; ++r) {
                float v = cc[j][r];
                if (kt == i && (kt * 64 + j * 16 + lq) > (trow0 + qd * 4 + r))
                    v = 0.f;             // strictly-future masked
                Ct[wave][qd * 4 + r][j * 16 + lq] = (bf16_t)v;
            }
        }
        // same-wave write->read: compiler-inserted lgkmcnt, no barrier

        // ---- phase 2: Y_sub += C . Kf_tile ----
        bf16x8 ca0 = *(const bf16x8*)&Ct[wave][lq][qd * 8];
        bf16x8 ca1 = *(const bf16x8*)&Ct[wave][lq][32 + qd * 8];
#pragma unroll
        for (int j = 0; j < 4; ++j) {
            acc[j] = mfma16(ca0, kb[2 * j], acc[j]);
            acc[j] = mfma16(ca1, kb[2 * j + 1], acc[j]);
        }
    }

    // ---- cross-parity reduce + epilogue ----
    if (par == 1) {
#pragma unroll
        for (int j = 0; j < 4; ++j)
#pragma unroll
            for (int r = 0; r < 4; ++r)
                Yred[sub][qd * 4 + r][j * 16 + lq] = acc[j][r];
    }
    __syncthreads();
    if (par == 0) {
#pragma unroll
        for (int j = 0; j < 4; ++j) {
#pragma unroll
            for (int r = 0; r < 4; ++r) {
                int trow_l = sub * 16 + qd * 4 + r;
                int tg = i * 64 + trow_l;
                float y = acc[j][r] + Yred[sub][qd * 4 + r][j * 16 + lq];
                y = y / (denb[trow_l] + 1e-6f);
                out[((size_t)b * TDIM + tg) * (8 * PDIM) + h * PDIM + j * 16 + lq] = y;
            }
        }
    }
}

// ---------------------------------------------------------------------------
extern "C" void kernel_launch(void* const* d_in, const int* in_sizes, int n_in,
                              void* d_out, int out_size, void* d_ws, size_t ws_size,
                              hipStream_t stream) {
    const float* Q = (const float*)d_in[0];
    const float* K = (const float*)d_in[1];
    const float* V = (const float*)d_in[2];
    float* out = (float*)d_out;

    bf16_t* Wf   = (bf16_t*)d_ws;                       // 2 MB
    bf16_t* Uf   = Wf + (size_t)BHN * TDIM * PDIM;      // 2 MB
    bf16_t* Kft  = Uf + (size_t)BHN * TDIM * PDIM;      // 2 MB
    float*  den  = (float*)(Kft + (size_t)BHN * TDIM * PDIM);  // 64 KB
    float*  cmax = den + (size_t)BHN * TDIM;            // 256 KB
    float*  csum = cmax + (size_t)BHN * NCH * PDIM;     // 256 KB

    stats_kernel<<<BHN * NCH, 64, 0, stream>>>(K, cmax, csum);
    feat_kernel<<<BHN * NCH, 64, 0, stream>>>(Q, K, V, cmax, csum, Wf, Uf, Kft, den);
    attn_kernel<<<256, 512, 0, stream>>>(Wf, Uf, Kft, den, out);
}

// Round 5
// 85.291 us; speedup vs baseline: 1.2156x; 1.2084x over previous
//
#include <hip/hip_runtime.h>
#include <hip/hip_bf16.h>

// Problem shape (fixed by setup_inputs): B=2, H=8, T=1024, P=64
#define TDIM 1024
#define PDIM 64
#define BHN  16     // B*H
#define NCH  64     // chunks along T
#define CHS  16     // chunk size (NCH*CHS == TDIM)

typedef __bf16 bf16_t;
typedef bf16_t bf16x8 __attribute__((ext_vector_type(8)));
typedef float  floatx4 __attribute__((ext_vector_type(4)));

__device__ __forceinline__ floatx4 mfma16(bf16x8 a, bf16x8 b, floatx4 c) {
    return __builtin_amdgcn_mfma_f32_16x16x32_bf16(a, b, c, 0, 0, 0);
}

// ---------------------------------------------------------------------------
// A1: per-(bh, chunk) stats: chunk max of K and chunk sum of exp(2K), per p.
// grid = BHN*NCH = 1024 blocks of 64 threads (lane = p) -> 4 waves/CU.
// ---------------------------------------------------------------------------
__global__ __launch_bounds__(64) void stats_kernel(
        const float* __restrict__ K,
        float* __restrict__ cmax, float* __restrict__ csum) {
    int bh = blockIdx.x >> 6;
    int c  = blockIdx.x & 63;
    int p  = threadIdx.x;
    const float* Kb = K + (size_t)bh * TDIM * PDIM + (size_t)c * CHS * PDIM + p;
    float k[CHS];
#pragma unroll
    for (int i = 0; i < CHS; ++i) k[i] = Kb[i * PDIM];
    float m = -INFINITY, s = 0.f;
#pragma unroll
    for (int i = 0; i < CHS; ++i) {
        m = fmaxf(m, k[i]);
        float e = __expf(k[i]);
        s += e * e;
    }
    cmax[(bh * NCH + c) * PDIM + p] = m;
    csum[(bh * NCH + c) * PDIM + p] = s;
}

// ---------------------------------------------------------------------------
// A2: seeded within-chunk sequential scan (CHS=16 steps). Emits:
//   W[bh][t][p]  = bf16( exp(Q - m_cum) )        (natural layout)
//   U[bh][t][p]  = bf16( V * exp(K) )            (natural layout)
//   Kft[bh][q][t]= bf16( exp(K[t][q]) )          (TRANSPOSED, via LDS tile)
//   den[bh][t]   = fp32 sum_p W*S2cum            (post-loop LDS reduce)
// grid = BHN*NCH = 1024 blocks of 64 threads (lane = p).
// ---------------------------------------------------------------------------
__global__ __launch_bounds__(64) void feat_kernel(
        const float* __restrict__ Q, const float* __restrict__ K,
        const float* __restrict__ V,
        const float* __restrict__ cmax, const float* __restrict__ csum,
        bf16_t* __restrict__ W, bf16_t* __restrict__ U,
        bf16_t* __restrict__ Kft, float* __restrict__ den) {
    int bh = blockIdx.x >> 6;
    int c  = blockIdx.x & 63;
    int p  = threadIdx.x;
    size_t base = (size_t)bh * TDIM * PDIM;
    int t0 = c * CHS;

    float m = -INFINITY, s = 0.f;
#pragma unroll 8
    for (int cc = 0; cc < c; ++cc) {
        m = fmaxf(m, cmax[(bh * NCH + cc) * PDIM + p]);
        s += csum[(bh * NCH + cc) * PDIM + p];
    }

    float kq[CHS], qq_[CHS], vv[CHS];
#pragma unroll
    for (int i = 0; i < CHS; ++i) {
        kq[i]  = K[base + (size_t)(t0 + i) * PDIM + p];
        qq_[i] = Q[base + (size_t)(t0 + i) * PDIM + p];
        vv[i]  = V[base + (size_t)(t0 + i) * PDIM + p];
    }

    __shared__ bf16_t ek_t[CHS][PDIM + 4];   // [t_local][p]
    __shared__ float  dt[CHS][PDIM + 1];     // per-(t,p) den contribution

#pragma unroll
    for (int i = 0; i < CHS; ++i) {
        int t = t0 + i;
        m = fmaxf(m, kq[i]);
        float ek = __expf(kq[i]);
        s += ek * ek;                         // inclusive running sum of exp(2K)
        float w = __expf(qq_[i] - m);         // inclusive running max
        W[base + (size_t)t * PDIM + p] = (bf16_t)w;
        U[base + (size_t)t * PDIM + p] = (bf16_t)(vv[i] * ek);
        ek_t[i][p] = (bf16_t)ek;
        dt[i][p] = w * s;
    }
    __syncthreads();

    // den reduce: lane l -> t = l>>2, g = l&3; partial over p = 4*i+g
    {
        int tl = p >> 2, g = p & 3;
        float d = 0.f;
#pragma unroll
        for (int i = 0; i < 16; ++i) d += dt[tl][i * 4 + g];
        d += __shfl_xor(d, 1);
        d += __shfl_xor(d, 2);
        if (g == 0) den[bh * TDIM + t0 + tl] = d;
    }

    // transposed Kft write
    {
        int hi = p >> 4, tl = p & 15;
#pragma unroll
        for (int it = 0; it < 16; ++it) {
            int q = it * 4 + hi;
            Kft[((size_t)bh * PDIM + q) * TDIM + t0 + tl] = ek_t[tl][q];
        }
    }
}

// ---------------------------------------------------------------------------
// B: per-(bh, 64-row tile) causal double matmul — LDS-staged + pipelined.
// 512 thr / 8 waves: wave = par*4 + sub. sub = 16-row substrip of the i-tile,
// par = kt parity. Each super-iteration stages TWO kt tiles (slots 0/1) into
// LDS once (coalesced 128B segments, shared by all waves — R3's direct-global
// fragment loads were 4x redundant + latency-exposed and cost +10us), while
// the NEXT super-iteration's tiles are register-prefetched so global latency
// hides under the 32 MFMAs of compute. Ct (per-wave C round-trip) and Yred
// (cross-parity reduce) share one LDS buffer, barrier-ordered.
// grid = i*16 + bh (256 blocks); bh&7 spreads XCDs, 2 bh/XCD fits L2.
// ---------------------------------------------------------------------------
__global__ __launch_bounds__(512) void attn_kernel(
        const bf16_t* __restrict__ W, const bf16_t* __restrict__ U,
        const bf16_t* __restrict__ Kft, const float* __restrict__ den,
        float* __restrict__ out) {
    int bh  = blockIdx.x & 15;
    int i   = blockIdx.x >> 4;   // row tile index 0..15
    int tid = threadIdx.x;
    int wave = tid >> 6, lane = tid & 63;
    int lq = lane & 15, qd = lane >> 4;
    int sub = wave & 3;          // substrip: rows [16*sub, 16*sub+16) of tile
    int par = wave >> 2;         // kt parity handled by this wave
    int b = bh >> 3, h = bh & 7;

    __shared__ bf16_t Wt[64][72];
    __shared__ bf16_t Ut[2][64][72];
    __shared__ bf16_t Kt[2][64][72];
    __shared__ __align__(16) char ctyraw[8 * 16 * 72 * 2];  // Ct / Yred union
    __shared__ float denb[64];
    bf16_t (*Ct)[16][72]  = (bf16_t (*)[16][72])ctyraw;
    float  (*Yred)[16][68] = (float (*)[16][68])ctyraw;

    size_t base = (size_t)bh * TDIM * PDIM;
    size_t kftb = (size_t)bh * PDIM * TDIM;
    int row = tid >> 3, c8 = (tid & 7) << 3;   // staging coords: 1 int4/thread

    // ---- stage Wt + denb; prefetch tiles kt=0,1 (always in-bounds) ----
    int4 wfrag = *(const int4*)(W + base + (size_t)(i * 64 + row) * PDIM + c8);
    int4 pu0 = *(const int4*)(U + base + (size_t)(0 * 64 + row) * PDIM + c8);
    int4 pk0 = *(const int4*)(Kft + kftb + (size_t)row * TDIM + 0 * 64 + c8);
    int4 pu1 = *(const int4*)(U + base + (size_t)(1 * 64 + row) * PDIM + c8);
    int4 pk1 = *(const int4*)(Kft + kftb + (size_t)row * TDIM + 1 * 64 + c8);
    *(int4*)&Wt[row][c8] = wfrag;
    if (tid < 64) denb[tid] = den[bh * TDIM + i * 64 + tid];
    __syncthreads();

    // hoist this wave's W A-fragments (rows sub*16+lq of the i-tile)
    bf16x8 a0 = *(const bf16x8*)&Wt[sub * 16 + lq][qd * 8];
    bf16x8 a1 = *(const bf16x8*)&Wt[sub * 16 + lq][32 + qd * 8];

    floatx4 acc[4];
#pragma unroll
    for (int j = 0; j < 4; ++j) acc[j] = (floatx4){0.f, 0.f, 0.f, 0.f};

    int niter = (i >> 1) + 1;
    for (int kt2 = 0; kt2 < niter; ++kt2) {
        __syncthreads();   // previous compute done reading Ut/Kt
        *(int4*)&Ut[0][row][c8] = pu0;
        *(int4*)&Kt[0][row][c8] = pk0;
        *(int4*)&Ut[1][row][c8] = pu1;
        *(int4*)&Kt[1][row][c8] = pk1;
        // prefetch next super-iteration (loads fly under this one's compute)
        if (kt2 + 1 < niter) {
            int ktn = 2 * kt2 + 2;
            int ktn1 = ktn + 1 > 15 ? 15 : ktn + 1;
            pu0 = *(const int4*)(U + base + (size_t)(ktn * 64 + row) * PDIM + c8);
            pk0 = *(const int4*)(Kft + kftb + (size_t)row * TDIM + ktn * 64 + c8);
            pu1 = *(const int4*)(U + base + (size_t)(ktn1 * 64 + row) * PDIM + c8);
            pk1 = *(const int4*)(Kft + kftb + (size_t)row * TDIM + ktn1 * 64 + c8);
        }
        __syncthreads();   // LDS tiles ready

        int kt = 2 * kt2 + par;
        if (kt <= i) {     // wave-uniform
            // ---- phase 1: C[16 x 64] = W_sub . U_tile^T ----
            floatx4 cc[4];
#pragma unroll
            for (int j = 0; j < 4; ++j) {
                bf16x8 b0 = *(const bf16x8*)&Ut[par][j * 16 + lq][qd * 8];
                bf16x8 b1 = *(const bf16x8*)&Ut[par][j * 16 + lq][32 + qd * 8];
                floatx4 t = (floatx4){0.f, 0.f, 0.f, 0.f};
                t = mfma16(a0, b0, t);
                t = mfma16(a1, b1, t);
                cc[j] = t;
            }
            // ---- causal mask + C -> per-wave LDS (C/D: row=qd*4+r, col=lq)
            int trow0 = i * 64 + sub * 16;
#pragma unroll
            for (int j = 0; j < 4; ++j) {
#pragma unroll
                for (int r = 0; r < 4; ++r) {
                    float v = cc[j][r];
                    if (kt == i && (kt * 64 + j * 16 + lq) > (trow0 + qd * 4 + r))
                        v = 0.f;
                    Ct[wave][qd * 4 + r][j * 16 + lq] = (bf16_t)v;
                }
            }
            // same-wave write->read: compiler lgkmcnt, no barrier
            bf16x8 ca0 = *(const bf16x8*)&Ct[wave][lq][qd * 8];
            bf16x8 ca1 = *(const bf16x8*)&Ct[wave][lq][32 + qd * 8];
            // ---- phase 2: Y_sub += C . Kf_tile ----
#pragma unroll
            for (int j = 0; j < 4; ++j) {
                bf16x8 kb0 = *(const bf16x8*)&Kt[par][j * 16 + lq][qd * 8];
                bf16x8 kb1 = *(const bf16x8*)&Kt[par][j * 16 + lq][32 + qd * 8];
                acc[j] = mfma16(ca0, kb0, acc[j]);
                acc[j] = mfma16(ca1, kb1, acc[j]);
            }
        }
    }

    // ---- cross-parity reduce (Yred aliases Ct; barriers order it) ----
    __syncthreads();
    if (par == 1) {
#pragma unroll
        for (int j = 0; j < 4; ++j)
#pragma unroll
            for (int r = 0; r < 4; ++r)
                Yred[sub][qd * 4 + r][j * 16 + lq] = acc[j][r];
    }
    __syncthreads();
    if (par == 0) {
#pragma unroll
        for (int j = 0; j < 4; ++j) {
#pragma unroll
            for (int r = 0; r < 4; ++r) {
                int trow_l = sub * 16 + qd * 4 + r;
                int tg = i * 64 + trow_l;
                float y = acc[j][r] + Yred[sub][qd * 4 + r][j * 16 + lq];
                y = y / (denb[trow_l] + 1e-6f);
                out[((size_t)b * TDIM + tg) * (8 * PDIM) + h * PDIM + j * 16 + lq] = y;
            }
        }
    }
}

// ---------------------------------------------------------------------------
extern "C" void kernel_launch(void* const* d_in, const int* in_sizes, int n_in,
                              void* d_out, int out_size, void* d_ws, size_t ws_size,
                              hipStream_t stream) {
    const float* Q = (const float*)d_in[0];
    const float* K = (const float*)d_in[1];
    const float* V = (const float*)d_in[2];
    float* out = (float*)d_out;

    bf16_t* Wf   = (bf16_t*)d_ws;                       // 2 MB
    bf16_t* Uf   = Wf + (size_t)BHN * TDIM * PDIM;      // 2 MB
    bf16_t* Kft  = Uf + (size_t)BHN * TDIM * PDIM;      // 2 MB
    float*  den  = (float*)(Kft + (size_t)BHN * TDIM * PDIM);  // 64 KB
    float*  cmax = den + (size_t)BHN * TDIM;            // 256 KB
    float*  csum = cmax + (size_t)BHN * NCH * PDIM;     // 256 KB

    stats_kernel<<<BHN * NCH, 64, 0, stream>>>(K, cmax, csum);
    feat_kernel<<<BHN * NCH, 64, 0, stream>>>(Q, K, V, cmax, csum, Wf, Uf, Kft, den);
    attn_kernel<<<256, 512, 0, stream>>>(Wf, Uf, Kft, den, out);
}